// Round 14
// baseline (135.751 us; speedup 1.0000x reference)
//
#include <hip/hip_runtime.h>
#include <hip/hip_bf16.h>

typedef unsigned short u16;
typedef unsigned int   u32;
typedef __attribute__((ext_vector_type(8)))  short bf16x8;
typedef __attribute__((ext_vector_type(16))) float f32x16;

#define N_S   8192
#define M_TOT 10240
#define SEGS  8
#define SEG   1024
#define QT    320     // 32-row q-tiles over M_TOT
#define SCRN_TRAIN 2080   // sum_{q=0}^{63}(q+1)
#define SCRN_BLKS  3104   // 2080 + 16*64

__device__ __forceinline__ u16 f2bf(float f) {
  u32 x = __float_as_uint(f);
  u32 r = x + 0x7FFFu + ((x >> 16) & 1u);
  return (u16)(r >> 16);
}
__device__ __forceinline__ float bf2f(u16 h) {
  return __uint_as_float(((u32)h) << 16);
}

// ---------------------------------------------------------------- x = A @ W^T + b (bf16 MFMA)
// cb<192 blocks emit their xb/hl chunk; cb==0 skips the dead x[:,0] store;
// cb==192 train tiles are dead -> early exit
__global__ __launch_bounds__(256) void gemm_x(const float* __restrict__ data,
                                              const float* __restrict__ inp,
                                              const float* __restrict__ W,
                                              const float* __restrict__ bias,
                                              float* __restrict__ x,
                                              u16* __restrict__ xb,
                                              u32* __restrict__ hl)
{
  __shared__ __align__(16) u16 At[64 * 256];   // 32KB, XOR-swizzled
  __shared__ __align__(16) u16 Wt[64 * 256];   // 32KB, XOR-swizzled
  __shared__ float part[64][2];
  const int t  = threadIdx.x;
  const int rb = blockIdx.x * 64, cb = blockIdx.y * 64;
  const int cbi = blockIdx.y;
  if (cb == 192 && rb + 64 <= N_S) return;     // dead tile: train rows, col-chunk 3

#pragma unroll
  for (int it = 0; it < 8; ++it) {
    int c = it * 256 + t;                    // chunk of 8 bf16
    int row = c >> 5, c8 = c & 31;
    int grow = rb + row;
    const float* src = (grow < N_S) ? data + (size_t)grow * 256 + c8 * 8
                                    : inp + (size_t)(grow - N_S) * 256 + c8 * 8;
    float4 v0 = *(const float4*)src;
    float4 v1 = *(const float4*)(src + 4);
    u16 h[8] = {f2bf(v0.x), f2bf(v0.y), f2bf(v0.z), f2bf(v0.w),
                f2bf(v1.x), f2bf(v1.y), f2bf(v1.z), f2bf(v1.w)};
    *(int4*)((char*)At + row * 512 + ((c8 * 16) ^ ((row & 7) << 4))) = *(int4*)h;

    const float* wsrc = W + (size_t)(cb + row) * 256 + c8 * 8;
    float4 w0 = *(const float4*)wsrc;
    float4 w1 = *(const float4*)(wsrc + 4);
    u16 g[8] = {f2bf(w0.x), f2bf(w0.y), f2bf(w0.z), f2bf(w0.w),
                f2bf(w1.x), f2bf(w1.y), f2bf(w1.z), f2bf(w1.w)};
    *(int4*)((char*)Wt + row * 512 + ((c8 * 16) ^ ((row & 7) << 4))) = *(int4*)g;
  }
  __syncthreads();

  const int w = t >> 6, lane = t & 63, l31 = lane & 31, hi = lane >> 5;
  const int wr = (w >> 1) * 32, wc = (w & 1) * 32;
  f32x16 acc;
#pragma unroll
  for (int r = 0; r < 16; ++r) acc[r] = 0.f;
  const char* Ab = (const char*)At + (size_t)(wr + l31) * 512;
  const char* Bb = (const char*)Wt + (size_t)(wc + l31) * 512;
  const int rx = (l31 & 7) << 4;
#pragma unroll
  for (int k0 = 0; k0 < 256; k0 += 16) {
    bf16x8 af = *(const bf16x8*)(Ab + ((k0 * 2 + hi * 16) ^ rx));
    bf16x8 bfv = *(const bf16x8*)(Bb + ((k0 * 2 + hi * 16) ^ rx));
    acc = __builtin_amdgcn_mfma_f32_32x32x16_bf16(af, bfv, acc, 0, 0, 0);
  }
  float bv = bias[cb + wc + l31];
  if (cb != 0) {     // x[:,0:64] is never read (xb0 emitted below) -> skip dead store
#pragma unroll
    for (int r = 0; r < 16; ++r) {
      int qr = (r & 3) + 8 * (r >> 2) + 4 * hi;
      x[(size_t)(rb + wr + qr) * 256 + cb + wc + l31] = acc[r] + bv;
    }
  }

  if (cb < 192) {      // emit xb chunk cbi (bf16) + per-row 0.5*|row|^2 Dekker split
    u16* xbc = xb + (size_t)cbi * ((size_t)M_TOT * 64);
    u32* hlc = hl + (size_t)cbi * M_TOT;
#pragma unroll
    for (int r = 0; r < 16; ++r) {
      int qr = (r & 3) + 8 * (r >> 2) + 4 * hi;
      u16 h = f2bf(acc[r] + bv);
      xbc[(size_t)(rb + wr + qr) * 64 + wc + l31] = h;
      float fb = bf2f(h);
      float s = fb * fb;
      s += __shfl_xor(s, 1);
      s += __shfl_xor(s, 2);
      s += __shfl_xor(s, 4);
      s += __shfl_xor(s, 8);
      s += __shfl_xor(s, 16);
      if (l31 == 0) part[wr + qr][w & 1] = s;
    }
    __syncthreads();
    if (t < 64) {
      float A = 0.5f * (part[t][0] + part[t][1]);
      u16 hq = f2bf(A);
      u16 lq = f2bf(A - bf2f(hq));
      hlc[rb + t] = (u32)hq | ((u32)lq << 16);
    }
  }
}

// ---------------------------------------------------------------- setup: prep_csT (blocks 0..383) + regw + mask/counter zero (384..447)
__global__ __launch_bounds__(256) void setup_ker(const float* __restrict__ css,
                                                 const float* __restrict__ W,
                                                 const float* __restrict__ bias,
                                                 u16* __restrict__ csbT,
                                                 float* __restrict__ regpart,
                                                 u32* __restrict__ mask,
                                                 u32* __restrict__ counter)
{
  __shared__ float tile[64][65];
  __shared__ float red[256];
  const int b = blockIdx.x, t = threadIdx.x;
  if (b < 384) {
    const int i  = b >> 7;
    const int r0 = (b & 127) * 64;
#pragma unroll
    for (int it = 0; it < 4; ++it) {
      int r  = (t >> 4) + it * 16;
      int c4 = (t & 15) * 4;
      float4 v = *(const float4*)(css + (size_t)(r0 + r) * 192 + i * 64 + c4);
      tile[r][c4] = v.x; tile[r][c4 + 1] = v.y; tile[r][c4 + 2] = v.z; tile[r][c4 + 3] = v.w;
    }
    __syncthreads();
    const int c = t >> 2, rq = (t & 3) * 16;
    u16 tmp[16];
#pragma unroll
    for (int e = 0; e < 16; ++e) tmp[e] = f2bf(tile[rq + e][c]);
    u16* dst = csbT + (size_t)i * (64 * (size_t)N_S) + (size_t)c * N_S + r0 + rq;
    *(int4*)dst       = *(int4*)tmp;
    *(int4*)(dst + 8) = *(int4*)(tmp + 8);
  } else {
    const int b2 = b - 384;
    const int gid = b2 * 256 + t;
    if (gid < 3 * QT * SEGS) mask[gid] = 0u;
    if (gid == 0) *counter = 0u;
    float4 v = *(const float4*)(W + (size_t)b2 * 1024 + t * 4);
    float s = v.x * v.x + v.y * v.y + v.z * v.z + v.w * v.w;
    if (b2 == 0) { float bv = bias[t]; s += bv * bv; }
    red[t] = s; __syncthreads();
#pragma unroll
    for (int o = 128; o; o >>= 1) {
      if (t < o) red[t] += red[t + o];
      __syncthreads();
    }
    if (t == 0) regpart[b2] = red[0];
  }
}

// ---------------------------------------------------------------- screen: activity bits, 4 qtiles x 4 k-tiles per wave
// COMPACT 1D grid; symmetry mirror via atomicOr (see R11/R13 notes)
__global__ __launch_bounds__(64) void screen_ker(const u16* __restrict__ xbj,
                                                 const u32* __restrict__ hlj,
                                                 u32* __restrict__ maskj)
{
  const int b = blockIdx.x;
  int qq, k;
  if (b < SCRN_TRAIN) {
    int q = (int)((sqrtf(8.0f * (float)b + 1.0f) - 1.0f) * 0.5f);
    while ((q + 1) * (q + 2) / 2 <= b) ++q;
    while (q * (q + 1) / 2 > b) --q;
    qq = q;
    k = b - q * (q + 1) / 2;
  } else {
    int b2 = b - SCRN_TRAIN;
    qq = 64 + (b2 >> 6);
    k = b2 & 63;
  }
  const int seg = k >> 3, w = k & 7;
  const int nt0 = seg * 32 + w * 4;

  const int lane = threadIdx.x & 63, l31 = lane & 31, hi = lane >> 5;

  bf16x8 qf[4][4];
  u32 hlq[4];
#pragma unroll
  for (int q = 0; q < 4; ++q) {
    const int qrow = (qq * 4 + q) * 32 + l31;
    const u16* qp = xbj + (size_t)qrow * 64 + hi * 8;
#pragma unroll
    for (int d = 0; d < 4; ++d) qf[q][d] = *(const bf16x8*)(qp + d * 16);
    hlq[q] = hlj[qrow];
  }

  f32x16 Z;
#pragma unroll
  for (int r = 0; r < 16; ++r) Z[r] = 0.f;

  u32 bits[4] = {0u, 0u, 0u, 0u};
#pragma unroll
  for (int it = 0; it < 4; ++it) {
    const int kt = nt0 + it;
    const int nb = kt * 32;
    const u16* kp = xbj + (size_t)(nb + l31) * 64 + hi * 8;
    bf16x8 kf0 = *(const bf16x8*)(kp);
    bf16x8 kf1 = *(const bf16x8*)(kp + 16);
    bf16x8 kf2 = *(const bf16x8*)(kp + 32);
    bf16x8 kf3 = *(const bf16x8*)(kp + 48);
    u32 hlk = hlj[nb + l31];
    union { bf16x8 v; u32 d[4]; } ke;
    ke.d[0] = hi ? 0u : 0xBF80BF80u;
    ke.d[1] = hi ? 0u : (hlk ^ 0x80008000u);
    ke.d[2] = 0u; ke.d[3] = 0u;
#pragma unroll
    for (int q = 0; q < 4; ++q) {
      f32x16 S = __builtin_amdgcn_mfma_f32_32x32x16_bf16(qf[q][0], kf0, Z, 0, 0, 0);
      S = __builtin_amdgcn_mfma_f32_32x32x16_bf16(qf[q][1], kf1, S, 0, 0, 0);
      S = __builtin_amdgcn_mfma_f32_32x32x16_bf16(qf[q][2], kf2, S, 0, 0, 0);
      S = __builtin_amdgcn_mfma_f32_32x32x16_bf16(qf[q][3], kf3, S, 0, 0, 0);
      union { bf16x8 v; u32 d[4]; } qe;
      qe.d[0] = hi ? 0u : hlq[q];
      qe.d[1] = hi ? 0u : 0x3F803F80u;
      qe.d[2] = 0u; qe.d[3] = 0u;
      S = __builtin_amdgcn_mfma_f32_32x32x16_bf16(qe.v, ke.v, S, 0, 0, 0);
      float m0 = fmaxf(S[0], S[1]),  m1 = fmaxf(S[2], S[3]);
      float m2 = fmaxf(S[4], S[5]),  m3 = fmaxf(S[6], S[7]);
      float m4 = fmaxf(S[8], S[9]),  m5 = fmaxf(S[10], S[11]);
      float m6 = fmaxf(S[12], S[13]), m7 = fmaxf(S[14], S[15]);
      float mx = fmaxf(fmaxf(fmaxf(m0, m1), fmaxf(m2, m3)),
                       fmaxf(fmaxf(m4, m5), fmaxf(m6, m7)));
      bool act = __any(mx > -25.0f) != 0;
      bits[q] |= (act ? 1u : 0u) << it;
      const int qtile = qq * 4 + q;
      if (act && qtile < 256 && kt < qtile && lane == 0)   // mirror (k,q)
        atomicOr(&maskj[(size_t)kt * SEGS + (qtile >> 5)], 1u << (qtile & 31));
    }
  }
  if (lane == 0) {
#pragma unroll
    for (int q = 0; q < 4; ++q)
      if (bits[q]) atomicOr(&maskj[(size_t)(qq * 4 + q) * SEGS + seg], bits[q] << (w * 4));
  }
}

// ---------------------------------------------------------------- fa: fused PV (4-wave split) + apply epilogue; anyu-guarded; NJ==3 adds final reduce
template<int NJ>
__global__ __launch_bounds__(256) void fa_ker(const u16* __restrict__ xb,
                                              const u32* __restrict__ hl,
                                              const u16* __restrict__ csbT,
                                              const u32* __restrict__ mask,
                                              const float* __restrict__ css,
                                              float* __restrict__ x,
                                              float* __restrict__ dotpart,
                                              u16* __restrict__ xbn,
                                              u32* __restrict__ hln,
                                              float* __restrict__ out,
                                              const float* __restrict__ regpart,
                                              u32* __restrict__ counter)
{
  __shared__ __align__(16) u16 Pt[4][32 * 32];     // per-wave P transpose buffer (8KB)
  __shared__ float accs[4][32][64];                // per-wave PV partials (32KB)
  __shared__ float red[256];
  __shared__ int lastFlag;

  const int t    = threadIdx.x;
  const int w    = t >> 6;
  const int lane = t & 63;
  const int l31  = lane & 31;
  const int hi   = lane >> 5;
  const int qtile = blockIdx.x;
  const int qrow  = qtile * 32 + l31;
  constexpr int I = NJ - 1;

  u32 mj_all[NJ][SEGS];
  u32 uni_s[SEGS];
  u32 anyu = 0;
#pragma unroll
  for (int seg = 0; seg < SEGS; ++seg) {
    u32 u = 0;
#pragma unroll
    for (int j = 0; j < NJ; ++j) {
      mj_all[j][seg] = mask[((size_t)j * QT + qtile) * SEGS + seg];
      u |= mj_all[j][seg];
    }
    uni_s[seg] = u;
    anyu |= u;
  }

  if (anyu) {
    bf16x8 qf[NJ][4];
    u32    hlq[NJ];
#pragma unroll
    for (int j = 0; j < NJ; ++j) {
      const u16* xbj = xb + (size_t)j * ((size_t)M_TOT * 64);
#pragma unroll
      for (int dk = 0; dk < 4; ++dk)
        qf[j][dk] = *(const bf16x8*)(xbj + (size_t)qrow * 64 + dk * 16 + hi * 8);
      hlq[j] = hl[j * M_TOT + qrow];
    }

    f32x16 acc0, acc1;
#pragma unroll
    for (int r = 0; r < 16; ++r) { acc0[r] = 0.f; acc1[r] = 0.f; }

    int idx = 0;
    for (int seg = 0; seg < SEGS; ++seg) {
      u32 rem = uni_s[seg];
      while (rem) {
        const int nt = __ffs(rem) - 1;
        rem &= rem - 1;
        if ((idx++ & 3) != w) continue;        // round-robin pairs across 4 waves
        const int nb = seg * SEG + nt * 32;
        f32x16 P;
#pragma unroll
        for (int r = 0; r < 16; ++r) P[r] = 0.f;
#pragma unroll
        for (int j = 0; j < NJ; ++j) {
          if ((mj_all[j][seg] >> nt) & 1u) {
            const u16* xbj = xb + (size_t)j * ((size_t)M_TOT * 64);
            const u16* kp = xbj + (size_t)(nb + l31) * 64 + hi * 8;
            bf16x8 kf0 = *(const bf16x8*)(kp);
            bf16x8 kf1 = *(const bf16x8*)(kp + 16);
            bf16x8 kf2 = *(const bf16x8*)(kp + 32);
            bf16x8 kf3 = *(const bf16x8*)(kp + 48);
            u32 hlk = hl[j * M_TOT + nb + l31];
            f32x16 S;
#pragma unroll
            for (int r = 0; r < 16; ++r) S[r] = 0.f;
            S = __builtin_amdgcn_mfma_f32_32x32x16_bf16(qf[j][0], kf0, S, 0, 0, 0);
            S = __builtin_amdgcn_mfma_f32_32x32x16_bf16(qf[j][1], kf1, S, 0, 0, 0);
            S = __builtin_amdgcn_mfma_f32_32x32x16_bf16(qf[j][2], kf2, S, 0, 0, 0);
            S = __builtin_amdgcn_mfma_f32_32x32x16_bf16(qf[j][3], kf3, S, 0, 0, 0);
            union { bf16x8 v; u32 d[4]; } qe, ke;
            qe.d[0] = hi ? 0u : hlq[j];
            qe.d[1] = hi ? 0u : 0x3F803F80u;
            qe.d[2] = 0u; qe.d[3] = 0u;
            ke.d[0] = hi ? 0u : 0xBF80BF80u;
            ke.d[1] = hi ? 0u : (hlk ^ 0x80008000u);
            ke.d[2] = 0u; ke.d[3] = 0u;
            S = __builtin_amdgcn_mfma_f32_32x32x16_bf16(qe.v, ke.v, S, 0, 0, 0);
#pragma unroll
            for (int r = 0; r < 16; ++r) P[r] += __expf(S[r]);
          }
        }
        char* pw = (char*)&Pt[w][0];
#pragma unroll
        for (int r = 0; r < 16; ++r) {
          int qr = (r & 3) + 8 * (r >> 2) + 4 * hi;
          *(u16*)(pw + qr * 64 + ((l31 * 2) ^ ((qr & 3) << 4))) = f2bf(P[r]);
        }
        asm volatile("s_waitcnt lgkmcnt(0)" ::: "memory");
        bf16x8 pa0 = *(const bf16x8*)(pw + l31 * 64 + ((0  + hi * 16) ^ ((l31 & 3) << 4)));
        bf16x8 pa1 = *(const bf16x8*)(pw + l31 * 64 + ((32 + hi * 16) ^ ((l31 & 3) << 4)));
        asm volatile("s_waitcnt lgkmcnt(0)" ::: "memory");   // drain before next tile's writes (WAR)
        bf16x8 v00 = *(const bf16x8*)(csbT + (size_t)l31 * N_S + nb + hi * 8);
        bf16x8 v01 = *(const bf16x8*)(csbT + (size_t)l31 * N_S + nb + 16 + hi * 8);
        bf16x8 v10 = *(const bf16x8*)(csbT + (size_t)(32 + l31) * N_S + nb + hi * 8);
        bf16x8 v11 = *(const bf16x8*)(csbT + (size_t)(32 + l31) * N_S + nb + 16 + hi * 8);
        acc0 = __builtin_amdgcn_mfma_f32_32x32x16_bf16(pa0, v00, acc0, 0, 0, 0);
        acc0 = __builtin_amdgcn_mfma_f32_32x32x16_bf16(pa1, v01, acc0, 0, 0, 0);
        acc1 = __builtin_amdgcn_mfma_f32_32x32x16_bf16(pa0, v10, acc1, 0, 0, 0);
        acc1 = __builtin_amdgcn_mfma_f32_32x32x16_bf16(pa1, v11, acc1, 0, 0, 0);
      }
    }

#pragma unroll
    for (int r = 0; r < 16; ++r) {
      int qr = (r & 3) + 8 * (r >> 2) + 4 * hi;
      accs[w][qr][l31]      = acc0[r];
      accs[w][qr][32 + l31] = acc1[r];
    }
    __syncthreads();
  }

  // -------- epilogue: 256 threads over 32 rows x 64 cols --------
  const int rr   = t >> 3;
  const int row  = qtile * 32 + rr;
  const int coff = (t & 7) * 8;
  float v[8];
#pragma unroll
  for (int e = 0; e < 8; ++e) v[e] = 0.f;
  float dp = 0.f;

  if (anyu) {
#pragma unroll
    for (int e = 0; e < 8; ++e)
      v[e] = ((accs[0][rr][coff + e] + accs[1][rr][coff + e]) +
              (accs[2][rr][coff + e] + accs[3][rr][coff + e]));
    if (row < N_S) {
      const float* cp = css + (size_t)row * 192 + (size_t)I * 64 + coff;
      float4 ca = *(const float4*)cp;
      float4 cb = *(const float4*)(cp + 4);
      dp = ca.x * v[0] + ca.y * v[1] + ca.z * v[2] + ca.w * v[3]
         + cb.x * v[4] + cb.y * v[5] + cb.z * v[6] + cb.w * v[7];
    }
  }

  if (NJ < 3) {
    if (anyu) {        // rows unchanged keep gemm's pre-emitted xb/hl (v==0)
      float* xp = x + (size_t)row * 256 + (size_t)(I + 1) * 64 + coff;
      float4 xa = *(const float4*)xp;
      float4 xb4 = *(const float4*)(xp + 4);
      xa.x += v[0]; xa.y += v[1]; xa.z += v[2]; xa.w += v[3];
      xb4.x += v[4]; xb4.y += v[5]; xb4.z += v[6]; xb4.w += v[7];
      *(float4*)xp = xa;
      *(float4*)(xp + 4) = xb4;
      float xv[8] = {xa.x, xa.y, xa.z, xa.w, xb4.x, xb4.y, xb4.z, xb4.w};
      u16 h[8];
      float s2 = 0.f;
#pragma unroll
      for (int e = 0; e < 8; ++e) {
        h[e] = f2bf(xv[e]);
        float fb = bf2f(h[e]);
        s2 += fb * fb;
      }
      *(int4*)(xbn + (size_t)row * 64 + coff) = *(int4*)h;
      s2 += __shfl_xor(s2, 1);
      s2 += __shfl_xor(s2, 2);
      s2 += __shfl_xor(s2, 4);
      if ((t & 7) == 0) {
        float A = 0.5f * s2;
        u16 hq = f2bf(A);
        u16 lq = f2bf(A - bf2f(hq));
        hln[row] = (u32)hq | ((u32)lq << 16);
      }
    }
  } else if (row >= N_S) {                 // out rows always written
    const float* xp = x + (size_t)row * 256 + 192 + coff;
    float4 xa = *(const float4*)xp;
    float4 xb4 = *(const float4*)(xp + 4);
    float* op = out + (size_t)(row - N_S) * 64 + coff;
    float4 oa = {xa.x + v[0], xa.y + v[1], xa.z + v[2], xa.w + v[3]};
    float4 ob = {xb4.x + v[4], xb4.y + v[5], xb4.z + v[6], xb4.w + v[7]};
    *(float4*)op = oa;
    *(float4*)(op + 4) = ob;
  }

  red[t] = dp; __syncthreads();
#pragma unroll
  for (int o = 128; o; o >>= 1) {
    if (t < o) red[t] += red[t + o];
    __syncthreads();
  }
  if (t == 0) dotpart[I * QT + qtile] = red[0];

  if (NJ == 3) {       // last block performs the global reg reduce
    if (t == 0) {
      u32 c = __hip_atomic_fetch_add(counter, 1u, __ATOMIC_ACQ_REL, __HIP_MEMORY_SCOPE_AGENT);
      lastFlag = (c == QT - 1) ? 1 : 0;
    }
    __syncthreads();
    if (lastFlag) {
      float s = 0.f;
      for (int i2 = t; i2 < 3 * QT; i2 += 256) s += dotpart[i2];
      if (t < 64) s += regpart[t];
      red[t] = s; __syncthreads();
#pragma unroll
      for (int o = 128; o; o >>= 1) {
        if (t < o) red[t] += red[t + o];
        __syncthreads();
      }
      if (t == 0) out[131072] = red[0];
    }
  }
}

// ================================================================ launch
extern "C" void kernel_launch(void* const* d_in, const int* in_sizes, int n_in,
                              void* d_out, int out_size, void* d_ws, size_t ws_size,
                              hipStream_t stream)
{
  const float* data = (const float*)d_in[0];
  const float* inp  = (const float*)d_in[1];
  const float* W    = (const float*)d_in[2];
  const float* bias = (const float*)d_in[3];
  const float* css  = (const float*)d_in[4];
  float* out = (float*)d_out;

  char* ws = (char*)d_ws;
  const size_t OFF_X    = 0;                         // 10,485,760
  const size_t OFF_XB   = 10485760;                  //  3,932,160
  const size_t OFF_HL   = OFF_XB + 3932160;          //    122,880
  const size_t OFF_CSBT = OFF_HL + 122880;           //  3,145,728
  const size_t OFF_MASK = OFF_CSBT + 3145728;        //     30,720
  const size_t OFF_REGW = OFF_MASK + 30720;          //        256
  const size_t OFF_DOT  = OFF_REGW + 256;            //      3,840
  const size_t OFF_CNT  = OFF_DOT + 3840;            //          4

  float* x      = (float*)(ws + OFF_X);
  u16*   xb     = (u16*)  (ws + OFF_XB);
  u32*   hl     = (u32*)  (ws + OFF_HL);
  u16*   csbT   = (u16*)  (ws + OFF_CSBT);
  u32*   mask   = (u32*)  (ws + OFF_MASK);
  float* regpart= (float*)(ws + OFF_REGW);
  float* dotpart= (float*)(ws + OFF_DOT);
  u32*   counter= (u32*)  (ws + OFF_CNT);

  const size_t XB_STRIDE = (size_t)M_TOT * 64;     // u16 elems
  const size_t CS_STRIDE = (size_t)64 * N_S;       // u16 elems
  const size_t MK_STRIDE = (size_t)QT * SEGS;      // u32 elems

  setup_ker<<<448, 256, 0, stream>>>(css, W, bias, csbT, regpart, mask, counter);
  gemm_x   <<<dim3(160, 4), 256, 0, stream>>>(data, inp, W, bias, x, xb, hl);
  screen_ker<<<SCRN_BLKS, 64, 0, stream>>>(xb, hl, mask);

  // i = 0: PV + x[:,1] + dot (+ re-emit changed xb1/hl1)
  fa_ker<1><<<QT, 256, 0, stream>>>(xb, hl, csbT, mask, css, x, dotpart,
                                    xb + XB_STRIDE, hl + M_TOT, (float*)nullptr,
                                    regpart, counter);
  screen_ker<<<SCRN_BLKS, 64, 0, stream>>>(xb + XB_STRIDE, hl + M_TOT, mask + MK_STRIDE);

  // i = 1: PV + x[:,2] + dot (+ re-emit changed xb2/hl2)
  fa_ker<2><<<QT, 256, 0, stream>>>(xb, hl, csbT + CS_STRIDE, mask, css, x, dotpart,
                                    xb + 2 * XB_STRIDE, hl + 2 * M_TOT, (float*)nullptr,
                                    regpart, counter);
  screen_ker<<<SCRN_BLKS, 64, 0, stream>>>(xb + 2 * XB_STRIDE, hl + 2 * M_TOT, mask + 2 * MK_STRIDE);

  // i = 2: PV + dot + direct out rows + final reduce (last block)
  fa_ker<3><<<QT, 256, 0, stream>>>(xb, hl, csbT + 2 * CS_STRIDE, mask, css, x, dotpart,
                                    (u16*)nullptr, (u32*)nullptr, out,
                                    regpart, counter);
}

// Round 15
// 133.821 us; speedup vs baseline: 1.0144x; 1.0144x over previous
//
#include <hip/hip_runtime.h>
#include <hip/hip_bf16.h>

typedef unsigned short u16;
typedef unsigned int   u32;
typedef __attribute__((ext_vector_type(8)))  short bf16x8;
typedef __attribute__((ext_vector_type(16))) float f32x16;

#define N_S   8192
#define M_TOT 10240
#define SEGS  8
#define SEG   1024
#define QT    320     // 32-row q-tiles over M_TOT
#define SCRN_TRAIN 2080   // sum_{q=0}^{63}(q+1)
#define SCRN_BLKS  3104   // 2080 + 16*64

__device__ __forceinline__ u16 f2bf(float f) {
  u32 x = __float_as_uint(f);
  u32 r = x + 0x7FFFu + ((x >> 16) & 1u);
  return (u16)(r >> 16);
}
__device__ __forceinline__ float bf2f(u16 h) {
  return __uint_as_float(((u32)h) << 16);
}

// ---------------------------------------------------------------- x = A @ W^T + b (bf16 MFMA); cb==0 blocks also emit xb0/hl0
// cb==3 tiles for train rows are dead (only test rows read x[:,192:256]) -> early exit
__global__ __launch_bounds__(256) void gemm_x(const float* __restrict__ data,
                                              const float* __restrict__ inp,
                                              const float* __restrict__ W,
                                              const float* __restrict__ bias,
                                              float* __restrict__ x,
                                              u16* __restrict__ xb0,
                                              u32* __restrict__ hl0)
{
  __shared__ __align__(16) u16 At[64 * 256];   // 32KB, XOR-swizzled
  __shared__ __align__(16) u16 Wt[64 * 256];   // 32KB, XOR-swizzled
  __shared__ float part[64][2];
  const int t  = threadIdx.x;
  const int rb = blockIdx.x * 64, cb = blockIdx.y * 64;
  if (cb == 192 && rb + 64 <= N_S) return;     // dead tile: train rows, col-chunk 3

#pragma unroll
  for (int it = 0; it < 8; ++it) {
    int c = it * 256 + t;                    // chunk of 8 bf16
    int row = c >> 5, c8 = c & 31;
    int grow = rb + row;
    const float* src = (grow < N_S) ? data + (size_t)grow * 256 + c8 * 8
                                    : inp + (size_t)(grow - N_S) * 256 + c8 * 8;
    float4 v0 = *(const float4*)src;
    float4 v1 = *(const float4*)(src + 4);
    u16 h[8] = {f2bf(v0.x), f2bf(v0.y), f2bf(v0.z), f2bf(v0.w),
                f2bf(v1.x), f2bf(v1.y), f2bf(v1.z), f2bf(v1.w)};
    *(int4*)((char*)At + row * 512 + ((c8 * 16) ^ ((row & 7) << 4))) = *(int4*)h;

    const float* wsrc = W + (size_t)(cb + row) * 256 + c8 * 8;
    float4 w0 = *(const float4*)wsrc;
    float4 w1 = *(const float4*)(wsrc + 4);
    u16 g[8] = {f2bf(w0.x), f2bf(w0.y), f2bf(w0.z), f2bf(w0.w),
                f2bf(w1.x), f2bf(w1.y), f2bf(w1.z), f2bf(w1.w)};
    *(int4*)((char*)Wt + row * 512 + ((c8 * 16) ^ ((row & 7) << 4))) = *(int4*)g;
  }
  __syncthreads();

  const int w = t >> 6, lane = t & 63, l31 = lane & 31, hi = lane >> 5;
  const int wr = (w >> 1) * 32, wc = (w & 1) * 32;
  f32x16 acc;
#pragma unroll
  for (int r = 0; r < 16; ++r) acc[r] = 0.f;
  const char* Ab = (const char*)At + (size_t)(wr + l31) * 512;
  const char* Bb = (const char*)Wt + (size_t)(wc + l31) * 512;
  const int rx = (l31 & 7) << 4;
#pragma unroll
  for (int k0 = 0; k0 < 256; k0 += 16) {
    bf16x8 af = *(const bf16x8*)(Ab + ((k0 * 2 + hi * 16) ^ rx));
    bf16x8 bfv = *(const bf16x8*)(Bb + ((k0 * 2 + hi * 16) ^ rx));
    acc = __builtin_amdgcn_mfma_f32_32x32x16_bf16(af, bfv, acc, 0, 0, 0);
  }
  float bv = bias[cb + wc + l31];
#pragma unroll
  for (int r = 0; r < 16; ++r) {
    int qr = (r & 3) + 8 * (r >> 2) + 4 * hi;
    x[(size_t)(rb + wr + qr) * 256 + cb + wc + l31] = acc[r] + bv;
  }

  if (cb == 0) {       // emit xb0 (bf16) + per-row 0.5*|row|^2 Dekker split
#pragma unroll
    for (int r = 0; r < 16; ++r) {
      int qr = (r & 3) + 8 * (r >> 2) + 4 * hi;
      u16 h = f2bf(acc[r] + bv);
      xb0[(size_t)(rb + wr + qr) * 64 + wc + l31] = h;
      float fb = bf2f(h);
      float s = fb * fb;
      s += __shfl_xor(s, 1);
      s += __shfl_xor(s, 2);
      s += __shfl_xor(s, 4);
      s += __shfl_xor(s, 8);
      s += __shfl_xor(s, 16);
      if (l31 == 0) part[wr + qr][w & 1] = s;
    }
    __syncthreads();
    if (t < 64) {
      float A = 0.5f * (part[t][0] + part[t][1]);
      u16 hq = f2bf(A);
      u16 lq = f2bf(A - bf2f(hq));
      hl0[rb + t] = (u32)hq | ((u32)lq << 16);
    }
  }
}

// ---------------------------------------------------------------- setup: prep_csT (blocks 0..383) + regw + mask/counter zero (384..447)
__global__ __launch_bounds__(256) void setup_ker(const float* __restrict__ css,
                                                 const float* __restrict__ W,
                                                 const float* __restrict__ bias,
                                                 u16* __restrict__ csbT,
                                                 float* __restrict__ regpart,
                                                 u32* __restrict__ mask,
                                                 u32* __restrict__ counter)
{
  __shared__ float tile[64][65];
  __shared__ float red[256];
  const int b = blockIdx.x, t = threadIdx.x;
  if (b < 384) {
    const int i  = b >> 7;
    const int r0 = (b & 127) * 64;
#pragma unroll
    for (int it = 0; it < 4; ++it) {
      int r  = (t >> 4) + it * 16;
      int c4 = (t & 15) * 4;
      float4 v = *(const float4*)(css + (size_t)(r0 + r) * 192 + i * 64 + c4);
      tile[r][c4] = v.x; tile[r][c4 + 1] = v.y; tile[r][c4 + 2] = v.z; tile[r][c4 + 3] = v.w;
    }
    __syncthreads();
    const int c = t >> 2, rq = (t & 3) * 16;
    u16 tmp[16];
#pragma unroll
    for (int e = 0; e < 16; ++e) tmp[e] = f2bf(tile[rq + e][c]);
    u16* dst = csbT + (size_t)i * (64 * (size_t)N_S) + (size_t)c * N_S + r0 + rq;
    *(int4*)dst       = *(int4*)tmp;
    *(int4*)(dst + 8) = *(int4*)(tmp + 8);
  } else {
    const int b2 = b - 384;
    const int gid = b2 * 256 + t;
    if (gid < 3 * QT * SEGS) mask[gid] = 0u;
    if (gid == 0) *counter = 0u;
    float4 v = *(const float4*)(W + (size_t)b2 * 1024 + t * 4);
    float s = v.x * v.x + v.y * v.y + v.z * v.z + v.w * v.w;
    if (b2 == 0) { float bv = bias[t]; s += bv * bv; }
    red[t] = s; __syncthreads();
#pragma unroll
    for (int o = 128; o; o >>= 1) {
      if (t < o) red[t] += red[t + o];
      __syncthreads();
    }
    if (t == 0) regpart[b2] = red[0];
  }
}

// ---------------------------------------------------------------- screen: activity bits, 4 qtiles x 4 k-tiles per wave
// COMPACT 1D grid: only needed blocks launched.
//  b < 2080: train qq = tri-decode(b), k = b - qq(qq+1)/2  (k = seg*8+w <= qq)
//  b >= 2080: test qq = 64 + (b-2080)/64, k = (b-2080)%64
// mirror: computed train pairs with kt<qtile atomicOr bit (kt,qtile).
__global__ __launch_bounds__(64) void screen_ker(const u16* __restrict__ xbj,
                                                 const u32* __restrict__ hlj,
                                                 u32* __restrict__ maskj)
{
  const int b = blockIdx.x;
  int qq, k;
  if (b < SCRN_TRAIN) {
    int q = (int)((sqrtf(8.0f * (float)b + 1.0f) - 1.0f) * 0.5f);
    while ((q + 1) * (q + 2) / 2 <= b) ++q;
    while (q * (q + 1) / 2 > b) --q;
    qq = q;
    k = b - q * (q + 1) / 2;
  } else {
    int b2 = b - SCRN_TRAIN;
    qq = 64 + (b2 >> 6);
    k = b2 & 63;
  }
  const int seg = k >> 3, w = k & 7;
  const int nt0 = seg * 32 + w * 4;

  const int lane = threadIdx.x & 63, l31 = lane & 31, hi = lane >> 5;

  bf16x8 qf[4][4];
  u32 hlq[4];
#pragma unroll
  for (int q = 0; q < 4; ++q) {
    const int qrow = (qq * 4 + q) * 32 + l31;
    const u16* qp = xbj + (size_t)qrow * 64 + hi * 8;
#pragma unroll
    for (int d = 0; d < 4; ++d) qf[q][d] = *(const bf16x8*)(qp + d * 16);
    hlq[q] = hlj[qrow];
  }

  f32x16 Z;
#pragma unroll
  for (int r = 0; r < 16; ++r) Z[r] = 0.f;

  u32 bits[4] = {0u, 0u, 0u, 0u};
#pragma unroll
  for (int it = 0; it < 4; ++it) {
    const int kt = nt0 + it;
    const int nb = kt * 32;
    const u16* kp = xbj + (size_t)(nb + l31) * 64 + hi * 8;
    bf16x8 kf0 = *(const bf16x8*)(kp);
    bf16x8 kf1 = *(const bf16x8*)(kp + 16);
    bf16x8 kf2 = *(const bf16x8*)(kp + 32);
    bf16x8 kf3 = *(const bf16x8*)(kp + 48);
    u32 hlk = hlj[nb + l31];
    union { bf16x8 v; u32 d[4]; } ke;
    ke.d[0] = hi ? 0u : 0xBF80BF80u;
    ke.d[1] = hi ? 0u : (hlk ^ 0x80008000u);
    ke.d[2] = 0u; ke.d[3] = 0u;
#pragma unroll
    for (int q = 0; q < 4; ++q) {
      f32x16 S = __builtin_amdgcn_mfma_f32_32x32x16_bf16(qf[q][0], kf0, Z, 0, 0, 0);
      S = __builtin_amdgcn_mfma_f32_32x32x16_bf16(qf[q][1], kf1, S, 0, 0, 0);
      S = __builtin_amdgcn_mfma_f32_32x32x16_bf16(qf[q][2], kf2, S, 0, 0, 0);
      S = __builtin_amdgcn_mfma_f32_32x32x16_bf16(qf[q][3], kf3, S, 0, 0, 0);
      union { bf16x8 v; u32 d[4]; } qe;
      qe.d[0] = hi ? 0u : hlq[q];
      qe.d[1] = hi ? 0u : 0x3F803F80u;
      qe.d[2] = 0u; qe.d[3] = 0u;
      S = __builtin_amdgcn_mfma_f32_32x32x16_bf16(qe.v, ke.v, S, 0, 0, 0);
      float m0 = fmaxf(S[0], S[1]),  m1 = fmaxf(S[2], S[3]);
      float m2 = fmaxf(S[4], S[5]),  m3 = fmaxf(S[6], S[7]);
      float m4 = fmaxf(S[8], S[9]),  m5 = fmaxf(S[10], S[11]);
      float m6 = fmaxf(S[12], S[13]), m7 = fmaxf(S[14], S[15]);
      float mx = fmaxf(fmaxf(fmaxf(m0, m1), fmaxf(m2, m3)),
                       fmaxf(fmaxf(m4, m5), fmaxf(m6, m7)));
      bool act = __any(mx > -25.0f) != 0;
      bits[q] |= (act ? 1u : 0u) << it;
      const int qtile = qq * 4 + q;
      if (act && qtile < 256 && kt < qtile && lane == 0)   // mirror (k,q)
        atomicOr(&maskj[(size_t)kt * SEGS + (qtile >> 5)], 1u << (qtile & 31));
    }
  }
  if (lane == 0) {
#pragma unroll
    for (int q = 0; q < 4; ++q)
      if (bits[q]) atomicOr(&maskj[(size_t)(qq * 4 + q) * SEGS + seg], bits[q] << (w * 4));
  }
}

// ---------------------------------------------------------------- fa: fused PV (4-wave split) + apply epilogue; NJ==3 adds final reduce
template<int NJ>
__global__ __launch_bounds__(256) void fa_ker(const u16* __restrict__ xb,
                                              const u32* __restrict__ hl,
                                              const u16* __restrict__ csbT,
                                              const u32* __restrict__ mask,
                                              const float* __restrict__ css,
                                              float* __restrict__ x,
                                              float* __restrict__ dotpart,
                                              u16* __restrict__ xbn,
                                              u32* __restrict__ hln,
                                              float* __restrict__ out,
                                              const float* __restrict__ regpart,
                                              u32* __restrict__ counter)
{
  __shared__ __align__(16) u16 Pt[4][32 * 32];     // per-wave P transpose buffer (8KB)
  __shared__ float accs[4][32][64];                // per-wave PV partials (32KB)
  __shared__ float red[256];
  __shared__ int lastFlag;

  const int t    = threadIdx.x;
  const int w    = t >> 6;
  const int lane = t & 63;
  const int l31  = lane & 31;
  const int hi   = lane >> 5;
  const int qtile = blockIdx.x;
  const int qrow  = qtile * 32 + l31;
  constexpr int I = NJ - 1;

  bf16x8 qf[NJ][4];
  u32    hlq[NJ];
#pragma unroll
  for (int j = 0; j < NJ; ++j) {
    const u16* xbj = xb + (size_t)j * ((size_t)M_TOT * 64);
#pragma unroll
    for (int dk = 0; dk < 4; ++dk)
      qf[j][dk] = *(const bf16x8*)(xbj + (size_t)qrow * 64 + dk * 16 + hi * 8);
    hlq[j] = hl[j * M_TOT + qrow];
  }

  f32x16 acc0, acc1;
#pragma unroll
  for (int r = 0; r < 16; ++r) { acc0[r] = 0.f; acc1[r] = 0.f; }

  int idx = 0;
  for (int seg = 0; seg < SEGS; ++seg) {
    u32 mj[NJ];
    u32 uni = 0;
#pragma unroll
    for (int j = 0; j < NJ; ++j) {
      mj[j] = mask[((size_t)j * QT + qtile) * SEGS + seg];
      uni |= mj[j];
    }
    u32 rem = uni;
    while (rem) {
      const int nt = __ffs(rem) - 1;
      rem &= rem - 1;
      if ((idx++ & 3) != w) continue;        // round-robin pairs across 4 waves
      const int nb = seg * SEG + nt * 32;
      f32x16 P;
#pragma unroll
      for (int r = 0; r < 16; ++r) P[r] = 0.f;
#pragma unroll
      for (int j = 0; j < NJ; ++j) {
        if ((mj[j] >> nt) & 1u) {
          const u16* xbj = xb + (size_t)j * ((size_t)M_TOT * 64);
          const u16* kp = xbj + (size_t)(nb + l31) * 64 + hi * 8;
          bf16x8 kf0 = *(const bf16x8*)(kp);
          bf16x8 kf1 = *(const bf16x8*)(kp + 16);
          bf16x8 kf2 = *(const bf16x8*)(kp + 32);
          bf16x8 kf3 = *(const bf16x8*)(kp + 48);
          u32 hlk = hl[j * M_TOT + nb + l31];
          f32x16 S;
#pragma unroll
          for (int r = 0; r < 16; ++r) S[r] = 0.f;
          S = __builtin_amdgcn_mfma_f32_32x32x16_bf16(qf[j][0], kf0, S, 0, 0, 0);
          S = __builtin_amdgcn_mfma_f32_32x32x16_bf16(qf[j][1], kf1, S, 0, 0, 0);
          S = __builtin_amdgcn_mfma_f32_32x32x16_bf16(qf[j][2], kf2, S, 0, 0, 0);
          S = __builtin_amdgcn_mfma_f32_32x32x16_bf16(qf[j][3], kf3, S, 0, 0, 0);
          union { bf16x8 v; u32 d[4]; } qe, ke;
          qe.d[0] = hi ? 0u : hlq[j];
          qe.d[1] = hi ? 0u : 0x3F803F80u;
          qe.d[2] = 0u; qe.d[3] = 0u;
          ke.d[0] = hi ? 0u : 0xBF80BF80u;
          ke.d[1] = hi ? 0u : (hlk ^ 0x80008000u);
          ke.d[2] = 0u; ke.d[3] = 0u;
          S = __builtin_amdgcn_mfma_f32_32x32x16_bf16(qe.v, ke.v, S, 0, 0, 0);
#pragma unroll
          for (int r = 0; r < 16; ++r) P[r] += __expf(S[r]);
        }
      }
      char* pw = (char*)&Pt[w][0];
#pragma unroll
      for (int r = 0; r < 16; ++r) {
        int qr = (r & 3) + 8 * (r >> 2) + 4 * hi;
        *(u16*)(pw + qr * 64 + ((l31 * 2) ^ ((qr & 3) << 4))) = f2bf(P[r]);
      }
      asm volatile("s_waitcnt lgkmcnt(0)" ::: "memory");
      bf16x8 pa0 = *(const bf16x8*)(pw + l31 * 64 + ((0  + hi * 16) ^ ((l31 & 3) << 4)));
      bf16x8 pa1 = *(const bf16x8*)(pw + l31 * 64 + ((32 + hi * 16) ^ ((l31 & 3) << 4)));
      asm volatile("s_waitcnt lgkmcnt(0)" ::: "memory");   // drain before next tile's writes (WAR)
      bf16x8 v00 = *(const bf16x8*)(csbT + (size_t)l31 * N_S + nb + hi * 8);
      bf16x8 v01 = *(const bf16x8*)(csbT + (size_t)l31 * N_S + nb + 16 + hi * 8);
      bf16x8 v10 = *(const bf16x8*)(csbT + (size_t)(32 + l31) * N_S + nb + hi * 8);
      bf16x8 v11 = *(const bf16x8*)(csbT + (size_t)(32 + l31) * N_S + nb + 16 + hi * 8);
      acc0 = __builtin_amdgcn_mfma_f32_32x32x16_bf16(pa0, v00, acc0, 0, 0, 0);
      acc0 = __builtin_amdgcn_mfma_f32_32x32x16_bf16(pa1, v01, acc0, 0, 0, 0);
      acc1 = __builtin_amdgcn_mfma_f32_32x32x16_bf16(pa0, v10, acc1, 0, 0, 0);
      acc1 = __builtin_amdgcn_mfma_f32_32x32x16_bf16(pa1, v11, acc1, 0, 0, 0);
    }
  }

#pragma unroll
  for (int r = 0; r < 16; ++r) {
    int qr = (r & 3) + 8 * (r >> 2) + 4 * hi;
    accs[w][qr][l31]      = acc0[r];
    accs[w][qr][32 + l31] = acc1[r];
  }
  __syncthreads();

  // -------- apply epilogue: 256 threads over 32 rows x 64 cols --------
  const int rr   = t >> 3;
  const int row  = qtile * 32 + rr;
  const int coff = (t & 7) * 8;
  float v[8];
#pragma unroll
  for (int e = 0; e < 8; ++e)
    v[e] = ((accs[0][rr][coff + e] + accs[1][rr][coff + e]) +
            (accs[2][rr][coff + e] + accs[3][rr][coff + e]));

  float dp = 0.f;
  if (row < N_S) {
    const float* cp = css + (size_t)row * 192 + (size_t)I * 64 + coff;
    float4 ca = *(const float4*)cp;
    float4 cb = *(const float4*)(cp + 4);
    dp = ca.x * v[0] + ca.y * v[1] + ca.z * v[2] + ca.w * v[3]
       + cb.x * v[4] + cb.y * v[5] + cb.z * v[6] + cb.w * v[7];
  }

  if (NJ < 3) {
    float* xp = x + (size_t)row * 256 + (size_t)(I + 1) * 64 + coff;
    float4 xa = *(const float4*)xp;
    float4 xb4 = *(const float4*)(xp + 4);
    xa.x += v[0]; xa.y += v[1]; xa.z += v[2]; xa.w += v[3];
    xb4.x += v[4]; xb4.y += v[5]; xb4.z += v[6]; xb4.w += v[7];
    *(float4*)xp = xa;
    *(float4*)(xp + 4) = xb4;
    float xv[8] = {xa.x, xa.y, xa.z, xa.w, xb4.x, xb4.y, xb4.z, xb4.w};
    u16 h[8];
    float s2 = 0.f;
#pragma unroll
    for (int e = 0; e < 8; ++e) {
      h[e] = f2bf(xv[e]);
      float fb = bf2f(h[e]);
      s2 += fb * fb;
    }
    *(int4*)(xbn + (size_t)row * 64 + coff) = *(int4*)h;
    s2 += __shfl_xor(s2, 1);
    s2 += __shfl_xor(s2, 2);
    s2 += __shfl_xor(s2, 4);
    if ((t & 7) == 0) {
      float A = 0.5f * s2;
      u16 hq = f2bf(A);
      u16 lq = f2bf(A - bf2f(hq));
      hln[row] = (u32)hq | ((u32)lq << 16);
    }
  } else if (row >= N_S) {
    const float* xp = x + (size_t)row * 256 + 192 + coff;
    float4 xa = *(const float4*)xp;
    float4 xb4 = *(const float4*)(xp + 4);
    float* op = out + (size_t)(row - N_S) * 64 + coff;
    float4 oa = {xa.x + v[0], xa.y + v[1], xa.z + v[2], xa.w + v[3]};
    float4 ob = {xb4.x + v[4], xb4.y + v[5], xb4.z + v[6], xb4.w + v[7]};
    *(float4*)op = oa;
    *(float4*)(op + 4) = ob;
  }

  red[t] = dp; __syncthreads();
#pragma unroll
  for (int o = 128; o; o >>= 1) {
    if (t < o) red[t] += red[t + o];
    __syncthreads();
  }
  if (t == 0) dotpart[I * QT + qtile] = red[0];

  if (NJ == 3) {       // last block performs the global reg reduce
    if (t == 0) {
      u32 c = __hip_atomic_fetch_add(counter, 1u, __ATOMIC_ACQ_REL, __HIP_MEMORY_SCOPE_AGENT);
      lastFlag = (c == QT - 1) ? 1 : 0;
    }
    __syncthreads();
    if (lastFlag) {
      float s = 0.f;
      for (int i2 = t; i2 < 3 * QT; i2 += 256) s += dotpart[i2];
      if (t < 64) s += regpart[t];
      red[t] = s; __syncthreads();
#pragma unroll
      for (int o = 128; o; o >>= 1) {
        if (t < o) red[t] += red[t + o];
        __syncthreads();
      }
      if (t == 0) out[131072] = red[0];
    }
  }
}

// ================================================================ launch
extern "C" void kernel_launch(void* const* d_in, const int* in_sizes, int n_in,
                              void* d_out, int out_size, void* d_ws, size_t ws_size,
                              hipStream_t stream)
{
  const float* data = (const float*)d_in[0];
  const float* inp  = (const float*)d_in[1];
  const float* W    = (const float*)d_in[2];
  const float* bias = (const float*)d_in[3];
  const float* css  = (const float*)d_in[4];
  float* out = (float*)d_out;

  char* ws = (char*)d_ws;
  const size_t OFF_X    = 0;                         // 10,485,760
  const size_t OFF_XB   = 10485760;                  //  3,932,160
  const size_t OFF_HL   = OFF_XB + 3932160;          //    122,880
  const size_t OFF_CSBT = OFF_HL + 122880;           //  3,145,728
  const size_t OFF_MASK = OFF_CSBT + 3145728;        //     30,720
  const size_t OFF_REGW = OFF_MASK + 30720;          //        256
  const size_t OFF_DOT  = OFF_REGW + 256;            //      3,840
  const size_t OFF_CNT  = OFF_DOT + 3840;            //          4

  float* x      = (float*)(ws + OFF_X);
  u16*   xb     = (u16*)  (ws + OFF_XB);
  u32*   hl     = (u32*)  (ws + OFF_HL);
  u16*   csbT   = (u16*)  (ws + OFF_CSBT);
  u32*   mask   = (u32*)  (ws + OFF_MASK);
  float* regpart= (float*)(ws + OFF_REGW);
  float* dotpart= (float*)(ws + OFF_DOT);
  u32*   counter= (u32*)  (ws + OFF_CNT);

  const size_t XB_STRIDE = (size_t)M_TOT * 64;     // u16 elems
  const size_t CS_STRIDE = (size_t)64 * N_S;       // u16 elems
  const size_t MK_STRIDE = (size_t)QT * SEGS;      // u32 elems

  setup_ker<<<448, 256, 0, stream>>>(css, W, bias, csbT, regpart, mask, counter);
  gemm_x   <<<dim3(160, 4), 256, 0, stream>>>(data, inp, W, bias, x, xb, hl);
  screen_ker<<<SCRN_BLKS, 64, 0, stream>>>(xb, hl, mask);

  // i = 0: PV + x[:,1] + dot + emit xb1/hl1
  fa_ker<1><<<QT, 256, 0, stream>>>(xb, hl, csbT, mask, css, x, dotpart,
                                    xb + XB_STRIDE, hl + M_TOT, (float*)nullptr,
                                    regpart, counter);
  screen_ker<<<SCRN_BLKS, 64, 0, stream>>>(xb + XB_STRIDE, hl + M_TOT, mask + MK_STRIDE);

  // i = 1: PV + x[:,2] + dot + emit xb2/hl2
  fa_ker<2><<<QT, 256, 0, stream>>>(xb, hl, csbT + CS_STRIDE, mask, css, x, dotpart,
                                    xb + 2 * XB_STRIDE, hl + 2 * M_TOT, (float*)nullptr,
                                    regpart, counter);
  screen_ker<<<SCRN_BLKS, 64, 0, stream>>>(xb + 2 * XB_STRIDE, hl + 2 * M_TOT, mask + 2 * MK_STRIDE);

  // i = 2: PV + dot + direct out rows + final reduce (last block)
  fa_ker<3><<<QT, 256, 0, stream>>>(xb, hl, csbT + 2 * CS_STRIDE, mask, css, x, dotpart,
                                    (u16*)nullptr, (u32*)nullptr, out,
                                    regpart, counter);
}